// Round 2
// baseline (129.195 us; speedup 1.0000x reference)
//
#include <hip/hip_runtime.h>
#include <math.h>

// Problem constants
#define NXD 64
#define NYD 48
#define NZD 32
#define NPT (NXD*NYD*NZD)   // 98304 points
#define PN  10              // neighbors per point
#define MF  5               // fourier modes
#define H1  64
#define H2  32
#define H3  8

// Block geometry: 256 threads = 4 waves; 32 points = 320 rows per block;
// each wave owns 8 points = 80 rows = 5 tiles of 16 rows.
#define PTS_PER_BLOCK 32
#define ROWS_PER_BLOCK (PTS_PER_BLOCK*PN)   // 320
#define TILES_PER_WAVE 5

// LDS strides (bf16 elements) — row stride multiple of 8 (16B) for ds_read_b128
#define A2S 72   // 16 rows x 72 (64 ch + pad)
#define A3S 40   // 16 rows x 40 (32 ch + pad)

#define INV2PI 0.15915494309189535f

typedef __attribute__((ext_vector_type(8))) short short8;  // 8 bf16 = 4 VGPRs
typedef __attribute__((ext_vector_type(4))) float f32x4;

// Per-(lg,j) feature descriptor for the PERMUTED K-ordering of layer 1.
// K-order chosen so each lane-group's 8 slots touch at most 2 coordinates:
//   lg0: [x,   s0x,s1x,s2x,s3x,s4x, c0x,c1x]            (cA=x, cB=x)
//   lg1: [y,   c2x,c3x,c4x, s0y,s1y,s2y,s3y]            (cA=x, cB=y)
//   lg2: [z,   s4y, c0y,c1y,c2y,c3y,c4y, s0z]           (cA=y, cB=z)
//   lg3: [s1z,s2z,s3z,s4z, c0z,c1z,c2z,c3z]             (cA=z, cB=z)
// leftover channel 32 = c4z (same rank-1 fixup as before).
// encoding: row(6b) | m(3b)<<6 | path(1b)<<9 | type(2b)<<10  (0=sin,1=cos,2=raw)
static __device__ const unsigned short kSlotTab[32] = {
  2048,    3,   70,  137,  204,  271, 1042, 1109,   // lg0
  2561, 1176, 1243, 1310,  516,  583,  650,  717,   // lg1
  2562,  272, 1043, 1110, 1177, 1244, 1311,  517,   // lg2
    72,  139,  206,  273, 1044, 1111, 1178, 1245 }; // lg3

// exact RNE fp32->bf16 (used only for one-time weight conversion)
__device__ __forceinline__ short f2bf(float f) {
    unsigned u = __float_as_uint(f);
    unsigned r = (u + 0x7fffu + ((u >> 16) & 1u)) >> 16;
    return (short)r;
}

// fast fp32->bf16, round-to-nearest (half-up on exact ties): 2 VALU
__device__ __forceinline__ unsigned short f2bf_hu(float f) {
    return (unsigned short)((__float_as_uint(f) + 0x8000u) >> 16);
}

// pack two fp32 -> one dword of 2 bf16 (lo in low half): 2 adds + v_perm
__device__ __forceinline__ unsigned pack2_bf16(float lo, float hi) {
    return __builtin_amdgcn_perm(__float_as_uint(hi) + 0x8000u,
                                 __float_as_uint(lo) + 0x8000u, 0x07060302u);
}

// tanh-form GELU, log2e folded into the polynomial so v_exp is called directly:
// gelu = x - x/(1+2^t), t = log2e*1.5957691*(x+0.044715x^3). 5 VALU + 2 trans.
__device__ __forceinline__ float gelu_fast(float x) {
    float x2 = x * x;
    float t  = x * (2.3022082f + 0.10294324f * x2);
    float E  = __builtin_amdgcn_exp2f(t);
    return x - x * __builtin_amdgcn_rcpf(E + 1.0f);
}

// tanh via 2^x: 1 - 2/(1+2^{2*log2e*v}); safe at both infinities
__device__ __forceinline__ float tanh_fast(float v) {
    float E = __builtin_amdgcn_exp2f(2.8853901f * v);
    return 1.0f - 2.0f * __builtin_amdgcn_rcpf(E + 1.0f);
}

__global__ __launch_bounds__(256) void domino_mfma_kernel(
    const float* __restrict__ x,      // (NPT*PN, 3)
    const float* __restrict__ freqs,  // (MF,)
    const float* __restrict__ W1,     // (33, 64)
    const float* __restrict__ b1,
    const float* __restrict__ W2,     // (64, 32)
    const float* __restrict__ b2,
    const float* __restrict__ W3,     // (32, 8)
    const float* __restrict__ b3,
    float* __restrict__ out)          // (8, NPT)
{
    __shared__ float obuf[ROWS_PER_BLOCK * 9];                  // masked tanh rows
    __shared__ __align__(16) unsigned short a2buf[4][16 * A2S]; // per-wave L1->L2 transpose
    __shared__ __align__(16) unsigned short a3buf[4][16 * A3S]; // per-wave L2->L3 transpose
    __shared__ __align__(16) float mcx[4][16];   // x-coordinate per row (mask)
    __shared__ __align__(16) float mv32[4][16];  // feature ch32 = cos(f4*z) per row

    const int tid  = threadIdx.x;
    const int w    = tid >> 6;      // wave id 0..3
    const int lane = tid & 63;
    const int lr   = lane & 15;     // A-row / B-col / C-col index
    const int lg   = lane >> 4;     // k-group / C-row-group

    // ---- per-lane slot constants (dedup'd feature gen; uniform hot-loop code)
    float fA[8], fB[8], offs[8];
    int   rowidx[8];
    float f4rev;
    {
        float fr[MF];
        #pragma unroll
        for (int m = 0; m < MF; ++m) fr[m] = freqs[m];
        f4rev = fr[4] * INV2PI;
        #pragma unroll
        for (int j = 0; j < 8; ++j) {
            const unsigned e = kSlotTab[lg*8 + j];
            const int row = e & 63, m = (e >> 6) & 7, path = (e >> 9) & 1, ty = (e >> 10) & 3;
            rowidx[j] = row;
            const float fm = fr[m] * INV2PI;
            fA[j]   = (ty != 2 && path == 0) ? fm : 0.0f;
            fB[j]   = (ty != 2 && path == 1) ? fm : 0.0f;
            offs[j] = (ty == 1) ? 0.25f : 0.0f;
        }
    }
    const float rawf = (lg < 3) ? 1.0f : 0.0f;   // slot0 is a raw coordinate for lg0..2

    // ---- preload weight fragments (once per wave)
    // B layout for 16x16x32: n = lane&15, k = (lane>>4)*8 + j ; k -> W1 row via rowidx
    short8 B1f[4];                      // layer1: K=32 (permuted), N=64 -> 4 n-tiles
    float  w32[4], bv1[4];              // ch32 rank-1 fixup weights + bias
    #pragma unroll
    for (int t1 = 0; t1 < 4; ++t1) {
        #pragma unroll
        for (int j = 0; j < 8; ++j)
            B1f[t1][j] = f2bf(W1[rowidx[j]*H1 + t1*16 + lr]);
        w32[t1] = W1[32*H1 + t1*16 + lr];
        bv1[t1] = b1[t1*16 + lr];
    }
    short8 B2f[2][2];                   // layer2: K=64 (2 steps), N=32 -> 2 n-tiles
    float  bv2[2];
    #pragma unroll
    for (int s = 0; s < 2; ++s)
        #pragma unroll
        for (int t2 = 0; t2 < 2; ++t2)
            #pragma unroll
            for (int j = 0; j < 8; ++j)
                B2f[s][t2][j] = f2bf(W2[(s*32 + lg*8 + j)*H2 + t2*16 + lr]);
    #pragma unroll
    for (int t2 = 0; t2 < 2; ++t2) bv2[t2] = b2[t2*16 + lr];

    short8 B3f;                         // layer3: K=32, N=16 (cols 8..15 zero)
    float  bv3 = (lr < H3) ? b3[lr] : 0.0f;
    #pragma unroll
    for (int j = 0; j < 8; ++j)
        B3f[j] = (lr < H3) ? f2bf(W3[(lg*8 + j)*H3 + lr]) : (short)0;

    const int wrow0 = blockIdx.x * ROWS_PER_BLOCK + w * (TILES_PER_WAVE*16);

    #pragma unroll 1
    for (int t = 0; t < TILES_PER_WAVE; ++t) {
        const int myrow = wrow0 + t*16 + lr;  // the A-row this lane generates

        // ---- load coords (4 lane-groups read the same 12B; L1 broadcast)
        const float* xp = x + (size_t)myrow * 3;
        const float cx = xp[0], cy = xp[1], cz = xp[2];

        // ---- per-lane two-coordinate select (uniform code, no divergence)
        const float cA = (lg <= 1) ? cx : ((lg == 2) ? cy : cz);
        const float cB = (lg == 0) ? cx : ((lg == 1) ? cy : cz);

        // ---- this lane's 8 features: 2 fma + fract + v_sin each (cos via +0.25 rev)
        float fv[8];
        #pragma unroll
        for (int j = 0; j < 8; ++j) {
            float rev = cA * fA[j] + (cB * fB[j] + offs[j]);
            fv[j] = __builtin_amdgcn_sinf(__builtin_amdgcn_fractf(rev));
        }
        // slot0 raw-coordinate override (raw coord is cB for lg0..2; no-op for lg3)
        fv[0] += rawf * (cB - fv[0]);

        // stage per-row mask coord and fixup feature ch32 = cos(f4*z)
        if (lg == 0) {
            mcx[w][lr]  = cx;
            mv32[w][lr] = __builtin_amdgcn_sinf(__builtin_amdgcn_fractf(cz * f4rev + 0.25f));
        }

        union { unsigned u[4]; short8 s8; } a1u;
        #pragma unroll
        for (int j = 0; j < 4; ++j) a1u.u[j] = pack2_bf16(fv[2*j], fv[2*j+1]);
        const short8 a1 = a1u.s8;

        // ---- Layer 1: 4 n-tiles, K=32, bias-initialized accumulators
        f32x4 c1[4];
        #pragma unroll
        for (int t1 = 0; t1 < 4; ++t1) {
            f32x4 ci = {bv1[t1], bv1[t1], bv1[t1], bv1[t1]};
            c1[t1] = __builtin_amdgcn_mfma_f32_16x16x32_bf16(a1, B1f[t1], ci, 0, 0, 0);
        }
        // ch32 rank-1 fixup + mask coords for this lane's 4 C-rows (float4 LDS reads)
        const f32x4 v32r = *(const f32x4*)&mv32[w][lg*4];
        const f32x4 mxr  = *(const f32x4*)&mcx[w][lg*4];
        #pragma unroll
        for (int t1 = 0; t1 < 4; ++t1)
            #pragma unroll
            for (int r = 0; r < 4; ++r)
                c1[t1][r] += v32r[r] * w32[t1];
        #pragma unroll
        for (int t1 = 0; t1 < 4; ++t1)
            #pragma unroll
            for (int r = 0; r < 4; ++r)
                c1[t1][r] = gelu_fast(c1[t1][r]);

        // ---- transpose L1 out (C-layout) -> A-layout via LDS
        #pragma unroll
        for (int t1 = 0; t1 < 4; ++t1)
            #pragma unroll
            for (int r = 0; r < 4; ++r)
                a2buf[w][(lg*4 + r)*A2S + t1*16 + lr] = f2bf_hu(c1[t1][r]);
        short8 a2f[2];
        #pragma unroll
        for (int s = 0; s < 2; ++s)
            a2f[s] = *(const short8*)&a2buf[w][lr*A2S + s*32 + lg*8];

        // ---- Layer 2: K=64 (2 steps), 2 n-tiles
        f32x4 c2[2];
        #pragma unroll
        for (int t2 = 0; t2 < 2; ++t2) {
            f32x4 ci = {bv2[t2], bv2[t2], bv2[t2], bv2[t2]};
            ci = __builtin_amdgcn_mfma_f32_16x16x32_bf16(a2f[0], B2f[0][t2], ci, 0, 0, 0);
            c2[t2] = __builtin_amdgcn_mfma_f32_16x16x32_bf16(a2f[1], B2f[1][t2], ci, 0, 0, 0);
        }
        #pragma unroll
        for (int t2 = 0; t2 < 2; ++t2)
            #pragma unroll
            for (int r = 0; r < 4; ++r)
                c2[t2][r] = gelu_fast(c2[t2][r]);

        // ---- transpose L2 out -> A-layout
        #pragma unroll
        for (int t2 = 0; t2 < 2; ++t2)
            #pragma unroll
            for (int r = 0; r < 4; ++r)
                a3buf[w][(lg*4 + r)*A3S + t2*16 + lr] = f2bf_hu(c2[t2][r]);
        short8 a3f = *(const short8*)&a3buf[w][lr*A3S + lg*8];

        // ---- Layer 3: K=32, N=16 (8 valid)
        f32x4 c3 = {bv3, bv3, bv3, bv3};
        c3 = __builtin_amdgcn_mfma_f32_16x16x32_bf16(a3f, B3f, c3, 0, 0, 0);

        // ---- tanh, mask, store per-row result to block buffer
        #pragma unroll
        for (int r = 0; r < 4; ++r) {
            const int brow = w*(TILES_PER_WAVE*16) + t*16 + lg*4 + r;
            const float mk = (fabsf(mxr[r]) > 1e-6f) ? 1.0f : 0.0f;
            if (lr < H3) obuf[brow*9 + lr] = mk * tanh_fast(c3[r]);
        }
    }

    __syncthreads();

    // ---- neighbor reduction: 32 points x 8 channels = 256 threads
    {
        const int p  = tid >> 3;   // 0..31
        const int ch = tid & 7;
        float sum = 0.0f;
        #pragma unroll
        for (int i = 0; i < PN; ++i) sum += obuf[(p*PN + i)*9 + ch];
        const int gp = blockIdx.x * PTS_PER_BLOCK + p;
        out[(size_t)ch * NPT + gp] = sum;
    }
}

extern "C" void kernel_launch(void* const* d_in, const int* in_sizes, int n_in,
                              void* d_out, int out_size, void* d_ws, size_t ws_size,
                              hipStream_t stream) {
    // setup_inputs order: x, grid(unused), freqs, W1, b1, W2, b2, W3, b3
    const float* x     = (const float*)d_in[0];
    const float* freqs = (const float*)d_in[2];
    const float* W1    = (const float*)d_in[3];
    const float* b1    = (const float*)d_in[4];
    const float* W2    = (const float*)d_in[5];
    const float* b2    = (const float*)d_in[6];
    const float* W3    = (const float*)d_in[7];
    const float* b3    = (const float*)d_in[8];
    float* out = (float*)d_out;

    const int grid = NPT / PTS_PER_BLOCK;   // 3072 blocks, no remainder
    domino_mfma_kernel<<<grid, 256, 0, stream>>>(x, freqs, W1, b1, W2, b2, W3, b3, out);
}

// Round 3
// 125.385 us; speedup vs baseline: 1.0304x; 1.0304x over previous
//
#include <hip/hip_runtime.h>
#include <math.h>

// Problem constants
#define NXD 64
#define NYD 48
#define NZD 32
#define NPT (NXD*NYD*NZD)   // 98304 points
#define PN  10              // neighbors per point
#define MF  5               // fourier modes
#define H1  64
#define H2  32
#define H3  8

// Block geometry: 256 threads = 4 waves; 32 points = 320 rows per block;
// each wave owns 8 points = 80 rows = 5 tiles of 16 rows.
#define PTS_PER_BLOCK 32
#define ROWS_PER_BLOCK (PTS_PER_BLOCK*PN)   // 320
#define TILES_PER_WAVE 5

// LDS strides (bf16 elements) — row stride multiple of 8 (16B) for ds_read_b128
#define A2S 72   // 16 rows x 72 (64 ch + pad)
#define A3S 40   // 16 rows x 40 (32 ch + pad) — ALIASED into a2buf's space

#define INV2PI 0.15915494309189535f

typedef __attribute__((ext_vector_type(8))) short short8;  // 8 bf16 = 4 VGPRs
typedef __attribute__((ext_vector_type(4))) float f32x4;

// Per-(lg,j) feature descriptor for the PERMUTED K-ordering of layer 1.
// K-order chosen so each lane-group's 8 slots touch at most 2 coordinates:
//   lg0: [x,   s0x,s1x,s2x,s3x,s4x, c0x,c1x]            (cA=x, cB=x)
//   lg1: [y,   c2x,c3x,c4x, s0y,s1y,s2y,s3y]            (cA=x, cB=y)
//   lg2: [z,   s4y, c0y,c1y,c2y,c3y,c4y, s0z]           (cA=y, cB=z)
//   lg3: [s1z,s2z,s3z,s4z, c0z,c1z,c2z,c3z]             (cA=z, cB=z)
// leftover channel 32 = c4z (rank-1 fixup).
// encoding: row(6b) | m(3b)<<6 | path(1b)<<9 | type(2b)<<10  (0=sin,1=cos,2=raw)
static __device__ const unsigned short kSlotTab[32] = {
  2048,    3,   70,  137,  204,  271, 1042, 1109,   // lg0
  2561, 1176, 1243, 1310,  516,  583,  650,  717,   // lg1
  2562,  272, 1043, 1110, 1177, 1244, 1311,  517,   // lg2
    72,  139,  206,  273, 1044, 1111, 1178, 1245 }; // lg3

// exact RNE fp32->bf16 (used only for one-time weight conversion)
__device__ __forceinline__ short f2bf(float f) {
    unsigned u = __float_as_uint(f);
    unsigned r = (u + 0x7fffu + ((u >> 16) & 1u)) >> 16;
    return (short)r;
}

// fast fp32->bf16, round-to-nearest (half-up on exact ties): 2 VALU
__device__ __forceinline__ unsigned short f2bf_hu(float f) {
    return (unsigned short)((__float_as_uint(f) + 0x8000u) >> 16);
}

// pack two fp32 -> one dword of 2 bf16 (lo in low half): 2 adds + v_perm
__device__ __forceinline__ unsigned pack2_bf16(float lo, float hi) {
    return __builtin_amdgcn_perm(__float_as_uint(hi) + 0x8000u,
                                 __float_as_uint(lo) + 0x8000u, 0x07060302u);
}

// tanh-form GELU, log2e folded so v_exp is called directly:
// gelu = x - x/(1+2^t), t = log2e*1.5957691*(x+0.044715x^3). 5 VALU + 2 trans.
__device__ __forceinline__ float gelu_fast(float x) {
    float x2 = x * x;
    float t  = x * (2.3022082f + 0.10294324f * x2);
    float E  = __builtin_amdgcn_exp2f(t);
    return x - x * __builtin_amdgcn_rcpf(E + 1.0f);
}

// tanh via 2^x: 1 - 2/(1+2^{2*log2e*v}); safe at both infinities
__device__ __forceinline__ float tanh_fast(float v) {
    float E = __builtin_amdgcn_exp2f(2.8853901f * v);
    return 1.0f - 2.0f * __builtin_amdgcn_rcpf(E + 1.0f);
}

__global__ __launch_bounds__(256) void domino_mfma_kernel(
    const float* __restrict__ x,      // (NPT*PN, 3)
    const float* __restrict__ freqs,  // (MF,)
    const float* __restrict__ W1,     // (33, 64)
    const float* __restrict__ b1,
    const float* __restrict__ W2,     // (64, 32)
    const float* __restrict__ b2,
    const float* __restrict__ W3,     // (32, 8)
    const float* __restrict__ b3,
    float* __restrict__ out)          // (8, NPT)
{
    // LDS budget (sum 20160 B -> 8 blocks/CU):
    __shared__ __align__(16) unsigned short a2buf[4][16 * A2S]; // 9216 B; low 1280 B/wave doubles as a3
    __shared__ __align__(16) float cbuf[976];                   // 3904 B staged coords (4 waves x 960B + tail slack)
    __shared__ __align__(16) _Float16 obuf[ROWS_PER_BLOCK * 9]; // 5760 B masked tanh rows
    __shared__ __align__(16) float mcx[4][16];                  // 256 B x-coordinate per row (mask)
    __shared__ __align__(16) float mv32[4][16];                 // 256 B feature ch32 = cos(f4*z)
    __shared__ __align__(16) float coefA[2][32];                // 256 B (x2 copies: (t&1) anti-hoist)
    __shared__ __align__(16) float coefB[2][32];                // 256 B
    __shared__ __align__(16) float coefO[2][32];                // 256 B

    const int tid  = threadIdx.x;
    const int w    = tid >> 6;      // wave id 0..3
    const int lane = tid & 63;
    const int lr   = lane & 15;     // A-row / B-col / C-col index
    const int lg   = lane >> 4;     // k-group / C-row-group

    const int wrow0 = blockIdx.x * ROWS_PER_BLOCK + w * (TILES_PER_WAVE*16);

    // ---- fill per-lg coefficient tables (32 threads; duplicated for (t&1) indexing)
    if (tid < 32) {
        const unsigned e = kSlotTab[tid];
        const int m = (e >> 6) & 7, path = (e >> 9) & 1, ty = (e >> 10) & 3;
        const float fm = freqs[m] * INV2PI;
        const float fa = (ty != 2 && path == 0) ? fm : 0.0f;
        const float fb = (ty != 2 && path == 1) ? fm : 0.0f;
        const float fo = (ty == 1) ? 0.25f : 0.0f;
        coefA[0][tid] = fa; coefA[1][tid] = fa;
        coefB[0][tid] = fb; coefB[1][tid] = fb;
        coefO[0][tid] = fo; coefO[1][tid] = fo;
    }

    // ---- stage this wave's 80 coord rows (960 B) into LDS: one global_load_lds dwordx4.
    // LDS dest is wave-uniform base + lane*16. Lanes 60-63 overflow 64B into the next
    // wave's region with IDENTICAL data (benign race); wave 3 clamps its tail lanes
    // (writes land in the 64B slack at cbuf[960..976), never read).
    {
        const int sl = (w == 3 && lane >= 60) ? 59 : lane;
        const float* gsrc = x + (size_t)wrow0 * 3 + (size_t)sl * 4;
        __builtin_amdgcn_global_load_lds(
            (const __attribute__((address_space(1))) void*)gsrc,
            (__attribute__((address_space(3))) void*)&cbuf[w * 240], 16, 0, 0);
    }

    const float f4rev = freqs[4] * INV2PI;
    const float rawf  = (lg < 3) ? 1.0f : 0.0f;   // slot0 is a raw coordinate for lg0..2

    // ---- preload weight fragments (once per wave)
    // B layout for 16x16x32: n = lane&15, k = (lane>>4)*8 + j ; k -> W1 row via slot table
    short8 B1f[4];                      // layer1: K=32 (permuted), N=64 -> 4 n-tiles
    float  w32[4], bv1[4];              // ch32 rank-1 fixup weights + bias
    #pragma unroll
    for (int t1 = 0; t1 < 4; ++t1) {
        #pragma unroll
        for (int j = 0; j < 8; ++j) {
            const int row = kSlotTab[lg*8 + j] & 63;
            B1f[t1][j] = f2bf(W1[row*H1 + t1*16 + lr]);
        }
        w32[t1] = W1[32*H1 + t1*16 + lr];
        bv1[t1] = b1[t1*16 + lr];
    }
    short8 B2f[2][2];                   // layer2: K=64 (2 steps), N=32 -> 2 n-tiles
    float  bv2[2];
    #pragma unroll
    for (int s = 0; s < 2; ++s)
        #pragma unroll
        for (int t2 = 0; t2 < 2; ++t2)
            #pragma unroll
            for (int j = 0; j < 8; ++j)
                B2f[s][t2][j] = f2bf(W2[(s*32 + lg*8 + j)*H2 + t2*16 + lr]);
    #pragma unroll
    for (int t2 = 0; t2 < 2; ++t2) bv2[t2] = b2[t2*16 + lr];

    short8 B3f;                         // layer3: K=32, N=16 (cols 8..15 zero)
    float  bv3 = (lr < H3) ? b3[lr] : 0.0f;
    #pragma unroll
    for (int j = 0; j < 8; ++j)
        B3f[j] = (lr < H3) ? f2bf(W3[(lg*8 + j)*H3 + lr]) : (short)0;

    // tables + staged coords visible to all waves (implies vmcnt/lgkmcnt drain)
    __syncthreads();

    #pragma unroll 1
    for (int t = 0; t < TILES_PER_WAVE; ++t) {
        // ---- coords from LDS (conflict-free: 3l mod 32 distinct; groups broadcast)
        const int cfx = w*240 + (t*16 + lr)*3;
        const float cx = cbuf[cfx + 0];
        const float cy = cbuf[cfx + 1];
        const float cz = cbuf[cfx + 2];

        // ---- per-lane two-coordinate select (uniform code, no divergence)
        const float cA = (lg <= 1) ? cx : ((lg == 2) ? cy : cz);
        const float cB = (lg == 0) ? cx : ((lg == 1) ? cy : cz);

        // ---- 8 features: 2 fma + fract + v_sin each; coefficients broadcast from LDS.
        // (t&1) alternates identical table copies so the reads can't be LICM-hoisted
        // back into persistent VGPRs. Two halves + sched_barrier cap transient pressure.
        const int tc = t & 1;
        float fv[8];
        {
            const f32x4 fa0 = *(const f32x4*)&coefA[tc][lg*8];
            const f32x4 fb0 = *(const f32x4*)&coefB[tc][lg*8];
            const f32x4 fo0 = *(const f32x4*)&coefO[tc][lg*8];
            #pragma unroll
            for (int j = 0; j < 4; ++j) {
                float rev = cA*fa0[j] + (cB*fb0[j] + fo0[j]);
                fv[j] = __builtin_amdgcn_sinf(__builtin_amdgcn_fractf(rev));
            }
        }
        __builtin_amdgcn_sched_barrier(0);
        {
            const f32x4 fa1 = *(const f32x4*)&coefA[tc][lg*8 + 4];
            const f32x4 fb1 = *(const f32x4*)&coefB[tc][lg*8 + 4];
            const f32x4 fo1 = *(const f32x4*)&coefO[tc][lg*8 + 4];
            #pragma unroll
            for (int j = 0; j < 4; ++j) {
                float rev = cA*fa1[j] + (cB*fb1[j] + fo1[j]);
                fv[4+j] = __builtin_amdgcn_sinf(__builtin_amdgcn_fractf(rev));
            }
        }
        // slot0 raw-coordinate override (raw coord is cB for lg0..2; no-op for lg3)
        fv[0] += rawf * (cB - fv[0]);

        // stage per-row mask coord and fixup feature ch32 = cos(f4*z)
        if (lg == 0) {
            mcx[w][lr]  = cx;
            mv32[w][lr] = __builtin_amdgcn_sinf(__builtin_amdgcn_fractf(cz * f4rev + 0.25f));
        }

        union { unsigned u[4]; short8 s8; } a1u;
        #pragma unroll
        for (int j = 0; j < 4; ++j) a1u.u[j] = pack2_bf16(fv[2*j], fv[2*j+1]);
        const short8 a1 = a1u.s8;

        // ---- Layer 1: 4 n-tiles, K=32, bias-initialized accumulators
        f32x4 c1[4];
        #pragma unroll
        for (int t1 = 0; t1 < 4; ++t1) {
            f32x4 ci = {bv1[t1], bv1[t1], bv1[t1], bv1[t1]};
            c1[t1] = __builtin_amdgcn_mfma_f32_16x16x32_bf16(a1, B1f[t1], ci, 0, 0, 0);
        }
        // ch32 rank-1 fixup + mask coords for this lane's 4 C-rows (float4 LDS reads)
        const f32x4 v32r = *(const f32x4*)&mv32[w][lg*4];
        const f32x4 mxr  = *(const f32x4*)&mcx[w][lg*4];
        #pragma unroll
        for (int t1 = 0; t1 < 4; ++t1)
            #pragma unroll
            for (int r = 0; r < 4; ++r)
                c1[t1][r] += v32r[r] * w32[t1];
        #pragma unroll
        for (int t1 = 0; t1 < 4; ++t1)
            #pragma unroll
            for (int r = 0; r < 4; ++r)
                c1[t1][r] = gelu_fast(c1[t1][r]);

        // ---- transpose L1 out (C-layout) -> A-layout via LDS
        #pragma unroll
        for (int t1 = 0; t1 < 4; ++t1)
            #pragma unroll
            for (int r = 0; r < 4; ++r)
                a2buf[w][(lg*4 + r)*A2S + t1*16 + lr] = f2bf_hu(c1[t1][r]);
        short8 a2f[2];
        #pragma unroll
        for (int s = 0; s < 2; ++s)
            a2f[s] = *(const short8*)&a2buf[w][lr*A2S + s*32 + lg*8];

        // ---- Layer 2: K=64 (2 steps), 2 n-tiles
        f32x4 c2[2];
        #pragma unroll
        for (int t2 = 0; t2 < 2; ++t2) {
            f32x4 ci = {bv2[t2], bv2[t2], bv2[t2], bv2[t2]};
            ci = __builtin_amdgcn_mfma_f32_16x16x32_bf16(a2f[0], B2f[0][t2], ci, 0, 0, 0);
            c2[t2] = __builtin_amdgcn_mfma_f32_16x16x32_bf16(a2f[1], B2f[1][t2], ci, 0, 0, 0);
        }
        #pragma unroll
        for (int t2 = 0; t2 < 2; ++t2)
            #pragma unroll
            for (int r = 0; r < 4; ++r)
                c2[t2][r] = gelu_fast(c2[t2][r]);

        // ---- transpose L2 out -> A-layout. Region ALIASES a2buf rows 0..8 of this
        // wave: safe — a2f reads completed (data-dep through L2 MFMA) before these
        // writes issue, and same-wave LDS ops are in-order.
        unsigned short* const a3p = &a2buf[w][0];
        #pragma unroll
        for (int t2 = 0; t2 < 2; ++t2)
            #pragma unroll
            for (int r = 0; r < 4; ++r)
                a3p[(lg*4 + r)*A3S + t2*16 + lr] = f2bf_hu(c2[t2][r]);
        short8 a3f = *(const short8*)&a3p[lr*A3S + lg*8];

        // ---- Layer 3: K=32, N=16 (8 valid)
        f32x4 c3 = {bv3, bv3, bv3, bv3};
        c3 = __builtin_amdgcn_mfma_f32_16x16x32_bf16(a3f, B3f, c3, 0, 0, 0);

        // ---- tanh, mask, store per-row result (fp16: |v|<=1, err ~5e-4)
        #pragma unroll
        for (int r = 0; r < 4; ++r) {
            const int brow = w*(TILES_PER_WAVE*16) + t*16 + lg*4 + r;
            const float mk = (fabsf(mxr[r]) > 1e-6f) ? 1.0f : 0.0f;
            if (lr < H3) obuf[brow*9 + lr] = (_Float16)(mk * tanh_fast(c3[r]));
        }
    }

    __syncthreads();

    // ---- neighbor reduction: 32 points x 8 channels = 256 threads
    {
        const int p  = tid >> 3;   // 0..31
        const int ch = tid & 7;
        float sum = 0.0f;
        #pragma unroll
        for (int i = 0; i < PN; ++i) sum += (float)obuf[(p*PN + i)*9 + ch];
        const int gp = blockIdx.x * PTS_PER_BLOCK + p;
        out[(size_t)ch * NPT + gp] = sum;
    }
}

extern "C" void kernel_launch(void* const* d_in, const int* in_sizes, int n_in,
                              void* d_out, int out_size, void* d_ws, size_t ws_size,
                              hipStream_t stream) {
    // setup_inputs order: x, grid(unused), freqs, W1, b1, W2, b2, W3, b3
    const float* x     = (const float*)d_in[0];
    const float* freqs = (const float*)d_in[2];
    const float* W1    = (const float*)d_in[3];
    const float* b1    = (const float*)d_in[4];
    const float* W2    = (const float*)d_in[5];
    const float* b2    = (const float*)d_in[6];
    const float* W3    = (const float*)d_in[7];
    const float* b3    = (const float*)d_in[8];
    float* out = (float*)d_out;

    const int grid = NPT / PTS_PER_BLOCK;   // 3072 blocks, no remainder
    domino_mfma_kernel<<<grid, 256, 0, stream>>>(x, freqs, W1, b1, W2, b2, W3, b3, out);
}

// Round 6
// 120.912 us; speedup vs baseline: 1.0685x; 1.0370x over previous
//
#include <hip/hip_runtime.h>
#include <math.h>

// Problem constants
#define NXD 64
#define NYD 48
#define NZD 32
#define NPT (NXD*NYD*NZD)   // 98304 points
#define PN  10              // neighbors per point
#define MF  5               // fourier modes
#define H1  64
#define H2  32
#define H3  8

// Block geometry: 256 threads = 4 waves; 32 points = 320 rows per block;
// each wave owns 8 points = 80 rows = 5 tiles of 16 rows.
#define PTS_PER_BLOCK 32
#define ROWS_PER_BLOCK (PTS_PER_BLOCK*PN)   // 320
#define TILES_PER_WAVE 5

// LDS strides (f16 elements) — row stride multiple of 8 (16B) for ds_read_b128
#define A2S 72   // 16 rows x 72 (64 ch + pad)
#define A3S 40   // 16 rows x 40 (32 ch + pad) — ALIASED into a2buf's space

#define INV2PI 0.15915494309189535f

typedef __attribute__((ext_vector_type(8))) _Float16 half8;   // 8 f16 = 4 VGPRs
typedef __attribute__((ext_vector_type(2))) _Float16 half2v;
typedef __attribute__((ext_vector_type(2))) __fp16   fp16x2;  // cvt_pkrtz return type
typedef __attribute__((ext_vector_type(2))) short    shortv2;
typedef __attribute__((ext_vector_type(4))) float    f32x4;

// pack two f32 -> half2v via v_cvt_pkrtz_f16_f32 (1 instr), bit-cast to _Float16 vec
__device__ __forceinline__ half2v cvt_pk_h2(float lo, float hi) {
    fp16x2 p = __builtin_amdgcn_cvt_pkrtz(lo, hi);
    return __builtin_bit_cast(half2v, p);
}

// Per-(lg,j) feature descriptor for the PERMUTED K-ordering of layer 1.
//   lg0: [x,   s0x,s1x,s2x,s3x,s4x, c0x,c1x]            (cA=x, cB=x)
//   lg1: [y,   c2x,c3x,c4x, s0y,s1y,s2y,s3y]            (cA=x, cB=y)
//   lg2: [z,   s4y, c0y,c1y,c2y,c3y,c4y, s0z]           (cA=y, cB=z)
//   lg3: [s1z,s2z,s3z,s4z, c0z,c1z,c2z,c3z]             (cA=z, cB=z)
// leftover channel 32 = c4z (rank-1 fixup).
// encoding: row(6b) | m(3b)<<6 | path(1b)<<9 | type(2b)<<10  (0=sin,1=cos,2=raw)
static __device__ const unsigned short kSlotTab[32] = {
  2048,    3,   70,  137,  204,  271, 1042, 1109,   // lg0
  2561, 1176, 1243, 1310,  516,  583,  650,  717,   // lg1
  2562,  272, 1043, 1110, 1177, 1244, 1311,  517,   // lg2
    72,  139,  206,  273, 1044, 1111, 1178, 1245 }; // lg3

// hardware f16 exp2 (trans pipe, 1 instr)
__device__ __forceinline__ _Float16 exp2h(_Float16 v) {
    _Float16 r;
    asm("v_exp_f16 %0, %1" : "=v"(r) : "v"(v));
    return r;
}

// Packed-f16 GELU on a pair of f32 pre-activations.
// gelu = x - x/(1+2^t), t = x*(2.3022082 + 0.10294324 x^2)  [tanh-form, log2e folded]
// reciprocal via f16 bit-trick guess (0x7800 - bits(y); exact at y=1,2; max err 12.5%)
// + 2 Newton steps -> 2.4e-4 rel. t clamped <=14 keeps y=1+2^t normal f16;
// t very negative -> E=0 -> y=1 -> r=1 -> gelu=0 exactly. 13 VALU + 2 trans per PAIR.
__device__ __forceinline__ half2v gelu_pk(float lo, float hi) {
    const _Float16 C1 = (_Float16)2.3022082f, C2 = (_Float16)0.10294324f;
    const half2v x  = cvt_pk_h2(lo, hi);
    const half2v x2 = x * x;
    half2v t = x * __builtin_elementwise_fma(x2, (half2v){C2, C2}, (half2v){C1, C1});
    t = __builtin_elementwise_min(t, (half2v){(_Float16)14.0f, (_Float16)14.0f});
    const _Float16 e0 = exp2h(t[0]);
    const _Float16 e1 = exp2h(t[1]);
    const half2v one = {(_Float16)1.0f, (_Float16)1.0f};
    const half2v two = {(_Float16)2.0f, (_Float16)2.0f};
    const half2v y = (half2v){e0, e1} + one;
    const shortv2 rb = (shortv2){(short)0x7800, (short)0x7800} - __builtin_bit_cast(shortv2, y);
    half2v r = __builtin_bit_cast(half2v, rb);
    r = r * __builtin_elementwise_fma(-y, r, two);
    r = r * __builtin_elementwise_fma(-y, r, two);
    return x - x * r;
}

// tanh via 2^x: 1 - 2/(1+2^{2*log2e*v}); safe at both infinities (f32 scalar, 4 lanes' worth)
__device__ __forceinline__ float tanh_fast(float v) {
    float E = __builtin_amdgcn_exp2f(2.8853901f * v);
    return 1.0f - 2.0f * __builtin_amdgcn_rcpf(E + 1.0f);
}

__global__ __launch_bounds__(256) void domino_mfma_kernel(
    const float* __restrict__ x,      // (NPT*PN, 3)
    const float* __restrict__ freqs,  // (MF,)
    const float* __restrict__ W1,     // (33, 64)
    const float* __restrict__ b1,
    const float* __restrict__ W2,     // (64, 32)
    const float* __restrict__ b2,
    const float* __restrict__ W3,     // (32, 8)
    const float* __restrict__ b3,
    float* __restrict__ out)          // (8, NPT)
{
    // LDS budget (sum 20160 B -> 8 blocks/CU):
    __shared__ __align__(16) _Float16 a2buf[4][16 * A2S];       // 9216 B; low 1280 B/wave doubles as a3
    __shared__ __align__(16) float cbuf[976];                   // 3904 B staged coords
    __shared__ __align__(16) _Float16 obuf[ROWS_PER_BLOCK * 9]; // 5760 B masked tanh rows
    __shared__ __align__(16) float mcx[4][16];                  // x-coordinate per row (mask)
    __shared__ __align__(16) float mv32[4][16];                 // feature ch32 = cos(f4*z)
    __shared__ __align__(16) float coefA[2][32];                // (x2 copies: (t&1) anti-hoist)
    __shared__ __align__(16) float coefB[2][32];
    __shared__ __align__(16) float coefO[2][32];

    const int tid  = threadIdx.x;
    const int w    = tid >> 6;      // wave id 0..3
    const int lane = tid & 63;
    const int lr   = lane & 15;     // A-row / B-col / C-col index
    const int lg   = lane >> 4;     // k-group / C-row-group

    const int wrow0 = blockIdx.x * ROWS_PER_BLOCK + w * (TILES_PER_WAVE*16);

    // ---- fill per-lg coefficient tables (32 threads; duplicated for (t&1) indexing)
    if (tid < 32) {
        const unsigned e = kSlotTab[tid];
        const int m = (e >> 6) & 7, path = (e >> 9) & 1, ty = (e >> 10) & 3;
        const float fm = freqs[m] * INV2PI;
        const float fa = (ty != 2 && path == 0) ? fm : 0.0f;
        const float fb = (ty != 2 && path == 1) ? fm : 0.0f;
        const float fo = (ty == 1) ? 0.25f : 0.0f;
        coefA[0][tid] = fa; coefA[1][tid] = fa;
        coefB[0][tid] = fb; coefB[1][tid] = fb;
        coefO[0][tid] = fo; coefO[1][tid] = fo;
    }

    // ---- stage this wave's 80 coord rows (960 B) into LDS: one global_load_lds dwordx4.
    // Lanes 60-63 overflow 64B into the next wave's region with IDENTICAL data (benign);
    // wave 3 clamps its tail lanes (writes land in the 64B slack, never read).
    {
        const int sl = (w == 3 && lane >= 60) ? 59 : lane;
        const float* gsrc = x + (size_t)wrow0 * 3 + (size_t)sl * 4;
        __builtin_amdgcn_global_load_lds(
            (const __attribute__((address_space(1))) void*)gsrc,
            (__attribute__((address_space(3))) void*)&cbuf[w * 240], 16, 0, 0);
    }

    const float f4rev = freqs[4] * INV2PI;
    const float rawf  = (lg < 3) ? 1.0f : 0.0f;   // slot0 is a raw coordinate for lg0..2

    // ---- preload weight fragments as f16 (once per wave)
    // B layout for 16x16x32: n = lane&15, k = (lane>>4)*8 + j ; k -> W1 row via slot table
    half8 B1f[4];                       // layer1: K=32 (permuted), N=64 -> 4 n-tiles
    float  w32[4], bv1[4];              // ch32 rank-1 fixup weights + bias
    #pragma unroll
    for (int t1 = 0; t1 < 4; ++t1) {
        #pragma unroll
        for (int j = 0; j < 8; ++j) {
            const int row = kSlotTab[lg*8 + j] & 63;
            B1f[t1][j] = (_Float16)W1[row*H1 + t1*16 + lr];
        }
        w32[t1] = W1[32*H1 + t1*16 + lr];
        bv1[t1] = b1[t1*16 + lr];
    }
    half8 B2f[2][2];                    // layer2: K=64 (2 steps), N=32 -> 2 n-tiles
    float  bv2[2];
    #pragma unroll
    for (int s = 0; s < 2; ++s)
        #pragma unroll
        for (int t2 = 0; t2 < 2; ++t2)
            #pragma unroll
            for (int j = 0; j < 8; ++j)
                B2f[s][t2][j] = (_Float16)W2[(s*32 + lg*8 + j)*H2 + t2*16 + lr];
    #pragma unroll
    for (int t2 = 0; t2 < 2; ++t2) bv2[t2] = b2[t2*16 + lr];

    half8 B3f;                          // layer3: K=32, N=16 (cols 8..15 zero)
    float  bv3 = (lr < H3) ? b3[lr] : 0.0f;
    #pragma unroll
    for (int j = 0; j < 8; ++j)
        B3f[j] = (lr < H3) ? (_Float16)W3[(lg*8 + j)*H3 + lr] : (_Float16)0.0f;

    // tables + staged coords visible to all waves (implies vmcnt/lgkmcnt drain)
    __syncthreads();

    #pragma unroll 1
    for (int t = 0; t < TILES_PER_WAVE; ++t) {
        // ---- coords from LDS (conflict-free; lane-groups broadcast)
        const int cfx = w*240 + (t*16 + lr)*3;
        const float cx = cbuf[cfx + 0];
        const float cy = cbuf[cfx + 1];
        const float cz = cbuf[cfx + 2];

        // ---- per-lane two-coordinate select (uniform code, no divergence)
        const float cA = (lg <= 1) ? cx : ((lg == 2) ? cy : cz);
        const float cB = (lg == 0) ? cx : ((lg == 1) ? cy : cz);

        // ---- 8 features: 2 fma + fract + v_sin each; coefficients broadcast from LDS.
        const int tc = t & 1;
        float fv[8];
        {
            const f32x4 fa0 = *(const f32x4*)&coefA[tc][lg*8];
            const f32x4 fb0 = *(const f32x4*)&coefB[tc][lg*8];
            const f32x4 fo0 = *(const f32x4*)&coefO[tc][lg*8];
            #pragma unroll
            for (int j = 0; j < 4; ++j) {
                float rev = cA*fa0[j] + (cB*fb0[j] + fo0[j]);
                fv[j] = __builtin_amdgcn_sinf(__builtin_amdgcn_fractf(rev));
            }
        }
        __builtin_amdgcn_sched_barrier(0);
        {
            const f32x4 fa1 = *(const f32x4*)&coefA[tc][lg*8 + 4];
            const f32x4 fb1 = *(const f32x4*)&coefB[tc][lg*8 + 4];
            const f32x4 fo1 = *(const f32x4*)&coefO[tc][lg*8 + 4];
            #pragma unroll
            for (int j = 0; j < 4; ++j) {
                float rev = cA*fa1[j] + (cB*fb1[j] + fo1[j]);
                fv[4+j] = __builtin_amdgcn_sinf(__builtin_amdgcn_fractf(rev));
            }
        }
        // slot0 raw-coordinate override (raw coord is cB for lg0..2; no-op for lg3)
        fv[0] += rawf * (cB - fv[0]);

        // stage per-row mask coord and fixup feature ch32 = cos(f4*z)
        if (lg == 0) {
            mcx[w][lr]  = cx;
            mv32[w][lr] = __builtin_amdgcn_sinf(__builtin_amdgcn_fractf(cz * f4rev + 0.25f));
        }

        // ---- pack features to f16 A-fragment (v_cvt_pkrtz: 1 op per pair)
        union { half2v h2[4]; half8 h8; } a1u;
        #pragma unroll
        for (int j = 0; j < 4; ++j)
            a1u.h2[j] = cvt_pk_h2(fv[2*j], fv[2*j+1]);
        const half8 a1 = a1u.h8;

        // ---- Layer 1: 4 n-tiles, K=32, bias-initialized accumulators (f16 MFMA)
        f32x4 c1[4];
        #pragma unroll
        for (int t1 = 0; t1 < 4; ++t1) {
            f32x4 ci = {bv1[t1], bv1[t1], bv1[t1], bv1[t1]};
            c1[t1] = __builtin_amdgcn_mfma_f32_16x16x32_f16(a1, B1f[t1], ci, 0, 0, 0);
        }
        // ch32 rank-1 fixup + mask coords for this lane's 4 C-rows (float4 LDS reads)
        const f32x4 v32r = *(const f32x4*)&mv32[w][lg*4];
        const f32x4 mxr  = *(const f32x4*)&mcx[w][lg*4];
        #pragma unroll
        for (int t1 = 0; t1 < 4; ++t1)
            #pragma unroll
            for (int r = 0; r < 4; ++r)
                c1[t1][r] += v32r[r] * w32[t1];

        // ---- packed gelu + transpose L1 out (C-layout) -> A-layout via LDS (f16)
        #pragma unroll
        for (int t1 = 0; t1 < 4; ++t1) {
            const half2v g01 = gelu_pk(c1[t1][0], c1[t1][1]);
            const half2v g23 = gelu_pk(c1[t1][2], c1[t1][3]);
            const int col = t1*16 + lr;
            a2buf[w][(lg*4 + 0)*A2S + col] = g01[0];
            a2buf[w][(lg*4 + 1)*A2S + col] = g01[1];
            a2buf[w][(lg*4 + 2)*A2S + col] = g23[0];
            a2buf[w][(lg*4 + 3)*A2S + col] = g23[1];
        }
        half8 a2f[2];
        #pragma unroll
        for (int s = 0; s < 2; ++s)
            a2f[s] = *(const half8*)&a2buf[w][lr*A2S + s*32 + lg*8];

        // ---- Layer 2: K=64 (2 steps), 2 n-tiles (f16 MFMA)
        f32x4 c2[2];
        #pragma unroll
        for (int t2 = 0; t2 < 2; ++t2) {
            f32x4 ci = {bv2[t2], bv2[t2], bv2[t2], bv2[t2]};
            ci = __builtin_amdgcn_mfma_f32_16x16x32_f16(a2f[0], B2f[0][t2], ci, 0, 0, 0);
            c2[t2] = __builtin_amdgcn_mfma_f32_16x16x32_f16(a2f[1], B2f[1][t2], ci, 0, 0, 0);
        }

        // ---- packed gelu + transpose L2 out -> A-layout. Region ALIASES a2buf rows
        // 0..8 of this wave: safe — a2f reads completed (data-dep through L2 MFMA)
        // before these writes issue, and same-wave LDS ops are in-order.
        _Float16* const a3p = &a2buf[w][0];
        #pragma unroll
        for (int t2 = 0; t2 < 2; ++t2) {
            const half2v g01 = gelu_pk(c2[t2][0], c2[t2][1]);
            const half2v g23 = gelu_pk(c2[t2][2], c2[t2][3]);
            const int col = t2*16 + lr;
            a3p[(lg*4 + 0)*A3S + col] = g01[0];
            a3p[(lg*4 + 1)*A3S + col] = g01[1];
            a3p[(lg*4 + 2)*A3S + col] = g23[0];
            a3p[(lg*4 + 3)*A3S + col] = g23[1];
        }
        half8 a3f = *(const half8*)&a3p[lr*A3S + lg*8];

        // ---- Layer 3: K=32, N=16 (8 valid)
        f32x4 c3 = {bv3, bv3, bv3, bv3};
        c3 = __builtin_amdgcn_mfma_f32_16x16x32_f16(a3f, B3f, c3, 0, 0, 0);

        // ---- tanh, mask, store per-row result (fp16: |v|<=1, err ~5e-4)
        #pragma unroll
        for (int r = 0; r < 4; ++r) {
            const int brow = w*(TILES_PER_WAVE*16) + t*16 + lg*4 + r;
            const float mk = (fabsf(mxr[r]) > 1e-6f) ? 1.0f : 0.0f;
            if (lr < H3) obuf[brow*9 + lr] = (_Float16)(mk * tanh_fast(c3[r]));
        }
    }

    __syncthreads();

    // ---- neighbor reduction: 32 points x 8 channels = 256 threads
    {
        const int p  = tid >> 3;   // 0..31
        const int ch = tid & 7;
        float sum = 0.0f;
        #pragma unroll
        for (int i = 0; i < PN; ++i) sum += (float)obuf[(p*PN + i)*9 + ch];
        const int gp = blockIdx.x * PTS_PER_BLOCK + p;
        out[(size_t)ch * NPT + gp] = sum;
    }
}

extern "C" void kernel_launch(void* const* d_in, const int* in_sizes, int n_in,
                              void* d_out, int out_size, void* d_ws, size_t ws_size,
                              hipStream_t stream) {
    // setup_inputs order: x, grid(unused), freqs, W1, b1, W2, b2, W3, b3
    const float* x     = (const float*)d_in[0];
    const float* freqs = (const float*)d_in[2];
    const float* W1    = (const float*)d_in[3];
    const float* b1    = (const float*)d_in[4];
    const float* W2    = (const float*)d_in[5];
    const float* b2    = (const float*)d_in[6];
    const float* W3    = (const float*)d_in[7];
    const float* b3    = (const float*)d_in[8];
    float* out = (float*)d_out;

    const int grid = NPT / PTS_PER_BLOCK;   // 3072 blocks, no remainder
    domino_mfma_kernel<<<grid, 256, 0, stream>>>(x, freqs, W1, b1, W2, b2, W3, b3, out);
}